// Round 6
// baseline (102.436 us; speedup 1.0000x reference)
//
#include <hip/hip_runtime.h>

// Problem constants
#define BB   8
#define CC   128
#define CR   16      // reduced channels = 128/8
#define HH   128
#define WW   128
#define HWSZ 16384   // 128*128
#define K2   9
#define NFRAG 72     // 8 ctiles * 9 taps

typedef _Float16 f16x8 __attribute__((ext_vector_type(8)));
typedef float    f32x4 __attribute__((ext_vector_type(4)));

// ws layout (float slots):
//   t     : [0, 2097152)             (b, cr, h, w) fp32
//   part  : [2097152, +16384)
//   stats : [2113536, +256)          (b,cr) x {scale,shift}
//   tn16  : [2113792, +1048576)      normalized t, f16, (b, hw, 16) packed
//   afrag : [3162368, +18432)        A fragments f16x8/lane (bias folded at kk=16)
#define WS_T     0
#define WS_PART  2097152
#define WS_STATS 2113536
#define WS_TN16  2113792
#define WS_AFRAG 3162368

__global__ __launch_bounds__(256) void k_conv1(const float* __restrict__ x,
                                               const float* __restrict__ w1,
                                               float* __restrict__ t,
                                               float* __restrict__ part) {
    const int tile = blockIdx.x;   // 0..63
    const int b    = blockIdx.y;   // 0..7
    const int tid  = threadIdx.x;
    const int pix  = tile * 256 + tid;

    __shared__ float w1s[CR * CC];   // 8 KB
    for (int i = tid; i < CR * CC; i += 256) w1s[i] = w1[i];
    __syncthreads();

    const float* xb = x + (size_t)b * CC * HWSZ + pix;
    float acc[CR];
#pragma unroll
    for (int o = 0; o < CR; ++o) acc[o] = 0.f;

    for (int cin = 0; cin < CC; ++cin) {
        float xv = xb[(size_t)cin * HWSZ];
#pragma unroll
        for (int o = 0; o < CR; ++o)
            acc[o] = fmaf(w1s[o * CC + cin], xv, acc[o]);
    }

    float* tb = t + (size_t)b * CR * HWSZ + pix;
#pragma unroll
    for (int o = 0; o < CR; ++o) tb[(size_t)o * HWSZ] = acc[o];

    __shared__ float red[4][CR][2];
    const int lane = tid & 63;
    const int wv   = tid >> 6;
#pragma unroll
    for (int o = 0; o < CR; ++o) {
        float s = acc[o];
        float q = s * s;
#pragma unroll
        for (int off = 32; off > 0; off >>= 1) {
            s += __shfl_down(s, off, 64);
            q += __shfl_down(q, off, 64);
        }
        if (lane == 0) { red[wv][o][0] = s; red[wv][o][1] = q; }
    }
    __syncthreads();
    if (tid < CR) {
        const int o = tid;
        float s = red[0][o][0] + red[1][o][0] + red[2][o][0] + red[3][o][0];
        float q = red[0][o][1] + red[1][o][1] + red[2][o][1] + red[3][o][1];
        const int blk = b * 64 + tile;
        part[blk * 32 + o * 2 + 0] = s;
        part[blk * 32 + o * 2 + 1] = q;
    }
}

// grid = 128 blocks (b*16+o), block = 64; wave-reduce over 64 tiles
__global__ void k_stats(const float* __restrict__ part,
                        const float* __restrict__ gamma,
                        const float* __restrict__ beta,
                        float* __restrict__ stats) {
    const int b   = blockIdx.x >> 4;
    const int o   = blockIdx.x & 15;
    const int tle = threadIdx.x;            // 0..63
    float s = part[(b * 64 + tle) * 32 + o * 2 + 0];
    float q = part[(b * 64 + tle) * 32 + o * 2 + 1];
#pragma unroll
    for (int off = 32; off > 0; off >>= 1) {
        s += __shfl_down(s, off, 64);
        q += __shfl_down(q, off, 64);
    }
    if (tle == 0) {
        const float mean = s * (1.f / (float)HWSZ);
        const float var  = q * (1.f / (float)HWSZ) - mean * mean;
        const float rstd = rsqrtf(var + 1e-5f);
        const float sc   = gamma[o] * rstd;
        const float sh   = beta[o] - mean * sc;
        stats[(b * CR + o) * 2 + 0] = sc;
        stats[(b * CR + o) * 2 + 1] = sh;
    }
}

// Normalize t -> packed f16 (b, hw, 16); one thread per pixel.
__global__ __launch_bounds__(256) void k_norm(const float* __restrict__ ws_t,
                                              const float* __restrict__ stats,
                                              f16x8* __restrict__ tn16) {
    const int p  = blockIdx.x * 256 + threadIdx.x;   // 0..131071
    const int b  = p >> 14;
    const int pp = p & 16383;
    const float* tb = ws_t + (size_t)b * CR * HWSZ + pp;
    const float* st = stats + b * CR * 2;
    f16x8 lo, hi;
#pragma unroll
    for (int i = 0; i < 8; ++i) {
        float v0 = fmaf(tb[(size_t)i * HWSZ],       st[i * 2],       st[i * 2 + 1]);
        float v1 = fmaf(tb[(size_t)(i + 8) * HWSZ], st[(i + 8) * 2], st[(i + 8) * 2 + 1]);
        lo[i] = (_Float16)(v0 > 0.f ? v0 : 0.f);
        hi[i] = (_Float16)(v1 > 0.f ? v1 : 0.f);
    }
    tn16[(size_t)p * 2 + 0] = lo;
    tn16[(size_t)p * 2 + 1] = hi;
}

// Pre-swizzle w2 into MFMA A-fragments (f16), bias folded at kk==16.
// A-frag (16x16x32_f16): lane holds A[row=lane&15][kk=8*(lane>>4)+i].
__global__ __launch_bounds__(256) void k_prep(const float* __restrict__ w2,
                                              const float* __restrict__ b2,
                                              float* __restrict__ ws) {
    const int id = blockIdx.x * 256 + threadIdx.x;
    if (id >= NFRAG * 64) return;
    const int lane = id & 63;
    const int frag = id >> 6;           // ct*9 + k
    const int ct = frag / 9, k = frag - ct * 9;
    const int row = lane & 15, lg = lane >> 4;
    f16x8 v;
#pragma unroll
    for (int i = 0; i < 8; ++i) {
        const int kk = lg * 8 + i;
        float w = 0.f;
        if (kk < CR)        w = w2[(size_t)((ct * 16 + row) * K2 + k) * CR + kk];
        else if (kk == CR)  w = b2[(ct * 16 + row) * K2 + k];
        v[i] = (_Float16)w;
    }
    f16x8* dst = (f16x8*)(ws + WS_AFRAG);
    dst[frag * 64 + lane] = v;
}

// Fused MFMA weight-gen + dilated 3x3 involution apply.
// Block: 4 waves x 16 px, 4-row strip, 32 channels (2 ctiles = blockIdx.z).
// grid = (32 ystrips * 2 xhalf, 8 b, 4 z); block = 256.
__global__ __launch_bounds__(256) void k_main(const float* __restrict__ x,
                                              const float* __restrict__ ws,
                                              float* __restrict__ out) {
    __shared__ f16x8 afl[18 * 64];   // 18432 B

    const int tid  = threadIdx.x;
    const int wv   = tid >> 6;
    const int lane = tid & 63;
    const int lg   = lane >> 4;           // 0..3
    const int ln   = lane & 15;
    const int xhalf  = blockIdx.x & 1;
    const int ystrip = blockIdx.x >> 1;
    const int y0   = ystrip * 4;
    const int colb = xhalf * 64 + wv * 16;
    const int col  = colb + ln;
    const int b    = blockIdx.y;
    const int z    = blockIdx.z;          // ctiles {2z, 2z+1}

    // ---- stage 18 A-frags into LDS ----
    {
        const float4* asrc = (const float4*)(ws + WS_AFRAG) + (size_t)z * 18 * 64;
        float4* adst = (float4*)afl;
        for (int i = tid; i < 18 * 64; i += 256) adst[i] = asrc[i];
    }

    // per-lane x offsets/masks; wave-uniform x interior flag
    int  xoff[3];
    bool xm[3];
#pragma unroll
    for (int j = 0; j < 3; ++j) {
        const int xx = col + (j * 2 - 2);
        xm[j]   = ((unsigned)xx < (unsigned)WW);
        xoff[j] = xx & (WW - 1);
    }
    const bool xint = (colb >= 2) && (colb + 15 < WW - 2);

    // prefetch B-fragments (normalized t, f16) for all 4 rows
    const f16x8* tns = (const f16x8*)(ws + WS_TN16);
    const f16x8 zerov = {};
    f16x8 onev = {};
    onev[0] = (_Float16)1.f;
    f16x8 tnf0, tnf1, tnf2, tnf3;
    if (lg < 2) {
        const size_t base = ((size_t)(b << 14) + (size_t)y0 * WW + col) * 2 + lg;
        tnf0 = tns[base];
        tnf1 = tns[base + 2 * WW];
        tnf2 = tns[base + 4 * WW];
        tnf3 = tns[base + 6 * WW];
    } else {
        const f16x8 v = (lg == 2) ? onev : zerov;
        tnf0 = v; tnf1 = v; tnf2 = v; tnf3 = v;
    }

    __syncthreads();

    const float* xb = x   + (size_t)b * CC * HWSZ;
    float*       ob = out + (size_t)b * CC * HWSZ;
    const int crow = lg * 4;
    const int cbase0 = z * 32 + crow;          // ctile 0 channel row base
    const int cbase1 = z * 32 + 16 + crow;     // ctile 1

#pragma unroll
    for (int r = 0; r < 4; ++r) {
        const int y = y0 + r;
        const f16x8 tnf = (r == 0) ? tnf0 : (r == 1) ? tnf1 : (r == 2) ? tnf2 : tnf3;

        int off[K2];
#pragma unroll
        for (int k = 0; k < K2; ++k) {
            const int yy = y + ((k / 3) * 2 - 2);
            off[k] = ((yy & (HH - 1)) << 7) + xoff[k % 3];
        }
        const bool yint  = (y >= 2) && (y < HH - 2);
        const bool allin = xint && yint;

        const float* xc0 = xb + (size_t)cbase0 * HWSZ;
        const float* xc1 = xb + (size_t)cbase1 * HWSZ;
        f32x4 acc0 = {0.f, 0.f, 0.f, 0.f};
        f32x4 acc1 = {0.f, 0.f, 0.f, 0.f};

        if (allin) {
#pragma unroll
            for (int k = 0; k < K2; ++k) {
                const f16x8 af0 = afl[k * 64 + lane];
                const f16x8 af1 = afl[(K2 + k) * 64 + lane];
                const f32x4 w0 = __builtin_amdgcn_mfma_f32_16x16x32_f16(af0, tnf, (f32x4){0.f,0.f,0.f,0.f}, 0, 0, 0);
                const f32x4 w1 = __builtin_amdgcn_mfma_f32_16x16x32_f16(af1, tnf, (f32x4){0.f,0.f,0.f,0.f}, 0, 0, 0);
                const float* p0 = xc0 + off[k];
                const float* p1 = xc1 + off[k];
#pragma unroll
                for (int reg = 0; reg < 4; ++reg) {
                    acc0[reg] = fmaf(w0[reg], p0[(size_t)reg * HWSZ], acc0[reg]);
                    acc1[reg] = fmaf(w1[reg], p1[(size_t)reg * HWSZ], acc1[reg]);
                }
            }
        } else {
#pragma unroll
            for (int k = 0; k < K2; ++k) {
                const int yy = y + ((k / 3) * 2 - 2);
                const float m = (xm[k % 3] && ((unsigned)yy < (unsigned)HH)) ? 1.f : 0.f;
                const f16x8 af0 = afl[k * 64 + lane];
                const f16x8 af1 = afl[(K2 + k) * 64 + lane];
                const f32x4 w0 = __builtin_amdgcn_mfma_f32_16x16x32_f16(af0, tnf, (f32x4){0.f,0.f,0.f,0.f}, 0, 0, 0);
                const f32x4 w1 = __builtin_amdgcn_mfma_f32_16x16x32_f16(af1, tnf, (f32x4){0.f,0.f,0.f,0.f}, 0, 0, 0);
                const float* p0 = xc0 + off[k];
                const float* p1 = xc1 + off[k];
#pragma unroll
                for (int reg = 0; reg < 4; ++reg) {
                    acc0[reg] = fmaf(w0[reg], p0[(size_t)reg * HWSZ] * m, acc0[reg]);
                    acc1[reg] = fmaf(w1[reg], p1[(size_t)reg * HWSZ] * m, acc1[reg]);
                }
            }
        }

        float* o0 = ob + (size_t)cbase0 * HWSZ + y * WW + col;
        float* o1 = ob + (size_t)cbase1 * HWSZ + y * WW + col;
#pragma unroll
        for (int reg = 0; reg < 4; ++reg) {
            o0[(size_t)reg * HWSZ] = acc0[reg];
            o1[(size_t)reg * HWSZ] = acc1[reg];
        }
    }
}

extern "C" void kernel_launch(void* const* d_in, const int* in_sizes, int n_in,
                              void* d_out, int out_size, void* d_ws, size_t ws_size,
                              hipStream_t stream) {
    const float* x     = (const float*)d_in[0];
    const float* w1    = (const float*)d_in[1];
    const float* gamma = (const float*)d_in[2];
    const float* beta  = (const float*)d_in[3];
    const float* w2    = (const float*)d_in[4];
    const float* b2    = (const float*)d_in[5];
    float* out = (float*)d_out;

    float* ws = (float*)d_ws;

    k_prep<<<18, 256, 0, stream>>>(w2, b2, ws);

    dim3 gA(64, 8);
    k_conv1<<<gA, 256, 0, stream>>>(x, w1, ws + WS_T, ws + WS_PART);

    k_stats<<<128, 64, 0, stream>>>(ws + WS_PART, gamma, beta, ws + WS_STATS);

    k_norm<<<512, 256, 0, stream>>>(ws + WS_T, ws + WS_STATS, (f16x8*)(ws + WS_TN16));

    dim3 gC(64, 8, 4);
    k_main<<<gC, 256, 0, stream>>>(x, ws, out);
}

// Round 7
// 96.826 us; speedup vs baseline: 1.0579x; 1.0579x over previous
//
#include <hip/hip_runtime.h>

// Problem constants
#define BB   8
#define CC   128
#define CR   16      // reduced channels = 128/8
#define HH   128
#define WW   128
#define HWSZ 16384   // 128*128
#define K2   9
#define NFRAG 72     // 8 ctiles * 9 taps

typedef _Float16 f16x8 __attribute__((ext_vector_type(8)));
typedef float    f32x4 __attribute__((ext_vector_type(4)));

// ws layout (float slots):
//   t     : [0, 2097152)             (b, cr, h, w) fp32
//   part  : [2097152, +16384)
//   stats : [2113536, +256)          (b,cr) x {scale,shift}
//   tn16  : [2113792, +1048576)      normalized t, f16, (b, hw, 16) packed
//   afrag : [3162368, +18432)        A fragments f16x8/lane (bias folded at kk=16)
#define WS_T     0
#define WS_PART  2097152
#define WS_STATS 2113536
#define WS_TN16  2113792
#define WS_AFRAG 3162368

__global__ __launch_bounds__(256) void k_conv1(const float* __restrict__ x,
                                               const float* __restrict__ w1,
                                               float* __restrict__ t,
                                               float* __restrict__ part) {
    const int tile = blockIdx.x;   // 0..63
    const int b    = blockIdx.y;   // 0..7
    const int tid  = threadIdx.x;
    const int pix  = tile * 256 + tid;

    __shared__ float w1s[CR * CC];   // 8 KB
    for (int i = tid; i < CR * CC; i += 256) w1s[i] = w1[i];
    __syncthreads();

    const float* xb = x + (size_t)b * CC * HWSZ + pix;
    float acc[CR];
#pragma unroll
    for (int o = 0; o < CR; ++o) acc[o] = 0.f;

    for (int cin = 0; cin < CC; ++cin) {
        float xv = xb[(size_t)cin * HWSZ];
#pragma unroll
        for (int o = 0; o < CR; ++o)
            acc[o] = fmaf(w1s[o * CC + cin], xv, acc[o]);
    }

    float* tb = t + (size_t)b * CR * HWSZ + pix;
#pragma unroll
    for (int o = 0; o < CR; ++o) tb[(size_t)o * HWSZ] = acc[o];

    __shared__ float red[4][CR][2];
    const int lane = tid & 63;
    const int wv   = tid >> 6;
#pragma unroll
    for (int o = 0; o < CR; ++o) {
        float s = acc[o];
        float q = s * s;
#pragma unroll
        for (int off = 32; off > 0; off >>= 1) {
            s += __shfl_down(s, off, 64);
            q += __shfl_down(q, off, 64);
        }
        if (lane == 0) { red[wv][o][0] = s; red[wv][o][1] = q; }
    }
    __syncthreads();
    if (tid < CR) {
        const int o = tid;
        float s = red[0][o][0] + red[1][o][0] + red[2][o][0] + red[3][o][0];
        float q = red[0][o][1] + red[1][o][1] + red[2][o][1] + red[3][o][1];
        const int blk = b * 64 + tile;
        part[blk * 32 + o * 2 + 0] = s;
        part[blk * 32 + o * 2 + 1] = q;
    }
}

// grid = 128 blocks (b*16+o), block = 64; wave-reduce over 64 tiles
__global__ void k_stats(const float* __restrict__ part,
                        const float* __restrict__ gamma,
                        const float* __restrict__ beta,
                        float* __restrict__ stats) {
    const int b   = blockIdx.x >> 4;
    const int o   = blockIdx.x & 15;
    const int tle = threadIdx.x;            // 0..63
    float s = part[(b * 64 + tle) * 32 + o * 2 + 0];
    float q = part[(b * 64 + tle) * 32 + o * 2 + 1];
#pragma unroll
    for (int off = 32; off > 0; off >>= 1) {
        s += __shfl_down(s, off, 64);
        q += __shfl_down(q, off, 64);
    }
    if (tle == 0) {
        const float mean = s * (1.f / (float)HWSZ);
        const float var  = q * (1.f / (float)HWSZ) - mean * mean;
        const float rstd = rsqrtf(var + 1e-5f);
        const float sc   = gamma[o] * rstd;
        const float sh   = beta[o] - mean * sc;
        stats[(b * CR + o) * 2 + 0] = sc;
        stats[(b * CR + o) * 2 + 1] = sh;
    }
}

// Normalize t -> packed f16 (b, hw, 16); one thread per pixel.
__global__ __launch_bounds__(256) void k_norm(const float* __restrict__ ws_t,
                                              const float* __restrict__ stats,
                                              f16x8* __restrict__ tn16) {
    const int p  = blockIdx.x * 256 + threadIdx.x;   // 0..131071
    const int b  = p >> 14;
    const int pp = p & 16383;
    const float* tb = ws_t + (size_t)b * CR * HWSZ + pp;
    const float* st = stats + b * CR * 2;
    f16x8 lo, hi;
#pragma unroll
    for (int i = 0; i < 8; ++i) {
        float v0 = fmaf(tb[(size_t)i * HWSZ],       st[i * 2],       st[i * 2 + 1]);
        float v1 = fmaf(tb[(size_t)(i + 8) * HWSZ], st[(i + 8) * 2], st[(i + 8) * 2 + 1]);
        lo[i] = (_Float16)(v0 > 0.f ? v0 : 0.f);
        hi[i] = (_Float16)(v1 > 0.f ? v1 : 0.f);
    }
    tn16[(size_t)p * 2 + 0] = lo;
    tn16[(size_t)p * 2 + 1] = hi;
}

// Pre-swizzle w2 into MFMA A-fragments (f16), bias folded at kk==16.
// A-frag (16x16x32_f16): lane holds A[row=lane&15][kk=8*(lane>>4)+i].
__global__ __launch_bounds__(256) void k_prep(const float* __restrict__ w2,
                                              const float* __restrict__ b2,
                                              float* __restrict__ ws) {
    const int id = blockIdx.x * 256 + threadIdx.x;
    if (id >= NFRAG * 64) return;
    const int lane = id & 63;
    const int frag = id >> 6;           // ct*9 + k
    const int ct = frag / 9, k = frag - ct * 9;
    const int row = lane & 15, lg = lane >> 4;
    f16x8 v;
#pragma unroll
    for (int i = 0; i < 8; ++i) {
        const int kk = lg * 8 + i;
        float w = 0.f;
        if (kk < CR)        w = w2[(size_t)((ct * 16 + row) * K2 + k) * CR + kk];
        else if (kk == CR)  w = b2[(ct * 16 + row) * K2 + k];
        v[i] = (_Float16)w;
    }
    f16x8* dst = (f16x8*)(ws + WS_AFRAG);
    dst[frag * 64 + lane] = v;
}

// Fused MFMA weight-gen + dilated 3x3 involution apply.
// Block: 4 waves x 16 px (64 px of ONE row) x 32 channels (2 ctiles).
// 1D grid 8192 with XCD-chunked swizzle: w = (bid&7)*1024 + bid>>3,
// w = ((b*4 + z)*2 + xhalf)*128 + y  (y innermost -> y-neighbor tap
// re-reads are same-XCD L2 hits).
__global__ __launch_bounds__(256) void k_main(const float* __restrict__ x,
                                              const float* __restrict__ ws,
                                              float* __restrict__ out) {
    __shared__ f16x8 afl[18 * 64];   // 18432 B

    const int bid = blockIdx.x;
    const int w   = (bid & 7) * 1024 + (bid >> 3);
    const int y     = w & 127;
    const int xhalf = (w >> 7) & 1;
    const int z     = (w >> 8) & 3;
    const int b     = w >> 10;

    const int tid  = threadIdx.x;
    const int wv   = tid >> 6;
    const int lane = tid & 63;
    const int lg   = lane >> 4;           // 0..3
    const int ln   = lane & 15;
    const int colb = xhalf * 64 + wv * 16;
    const int col  = colb + ln;

    // ---- stage 18 A-frags into LDS ----
    {
        const float4* asrc = (const float4*)(ws + WS_AFRAG) + (size_t)z * 18 * 64;
        float4* adst = (float4*)afl;
        for (int i = tid; i < 18 * 64; i += 256) adst[i] = asrc[i];
    }

    // B-fragment: one 16B load of packed normalized t (bias lane kk==16 -> 1)
    const f16x8* tns = (const f16x8*)(ws + WS_TN16);
    f16x8 tnf = {};
    if (lg < 2) {
        tnf = tns[((size_t)(b << 14) + (size_t)y * WW + col) * 2 + lg];
    } else if (lg == 2) {
        tnf[0] = (_Float16)1.f;
    }

    const bool yint = (y >= 2) && (y < HH - 2);
    const bool xint = (colb >= 2) && (colb + 17 < WW);
    const bool allin = xint && yint;

    __syncthreads();

    const float* xb = x   + (size_t)b * CC * HWSZ;
    float*       ob = out + (size_t)b * CC * HWSZ;
    const int crow = lg * 4;
    const int cb0  = z * 32 + crow;        // ctile 0 channel rows
    const int cb1  = cb0 + 16;             // ctile 1

    f32x4 acc0 = {0.f, 0.f, 0.f, 0.f};
    f32x4 acc1 = {0.f, 0.f, 0.f, 0.f};
    const f32x4 zc = {0.f, 0.f, 0.f, 0.f};

    if (allin) {
        // hoisted per-reg base pointers; taps become immediate offsets
        const float* p0[4];
        const float* p1[4];
#pragma unroll
        for (int reg = 0; reg < 4; ++reg) {
            p0[reg] = xb + (size_t)(cb0 + reg) * HWSZ + y * WW + col;
            p1[reg] = xb + (size_t)(cb1 + reg) * HWSZ + y * WW + col;
        }
#pragma unroll
        for (int k = 0; k < K2; ++k) {
            const int d = ((k / 3) * 2 - 2) * WW + ((k % 3) * 2 - 2);  // compile-time
            const f16x8 af0 = afl[k * 64 + lane];
            const f16x8 af1 = afl[(K2 + k) * 64 + lane];
            const f32x4 w0 = __builtin_amdgcn_mfma_f32_16x16x32_f16(af0, tnf, zc, 0, 0, 0);
            const f32x4 w1 = __builtin_amdgcn_mfma_f32_16x16x32_f16(af1, tnf, zc, 0, 0, 0);
#pragma unroll
            for (int reg = 0; reg < 4; ++reg) {
                acc0[reg] = fmaf(w0[reg], p0[reg][d], acc0[reg]);
                acc1[reg] = fmaf(w1[reg], p1[reg][d], acc1[reg]);
            }
        }
    } else {
        int   xoff[3];
        bool  xm[3];
#pragma unroll
        for (int j = 0; j < 3; ++j) {
            const int xx = col + (j * 2 - 2);
            xm[j]   = ((unsigned)xx < (unsigned)WW);
            xoff[j] = xx & (WW - 1);
        }
        const float* xc0 = xb + (size_t)cb0 * HWSZ;
        const float* xc1 = xb + (size_t)cb1 * HWSZ;
#pragma unroll
        for (int k = 0; k < K2; ++k) {
            const int yy = y + ((k / 3) * 2 - 2);
            const int off = ((yy & (HH - 1)) << 7) + xoff[k % 3];
            const float m = (xm[k % 3] && ((unsigned)yy < (unsigned)HH)) ? 1.f : 0.f;
            const f16x8 af0 = afl[k * 64 + lane];
            const f16x8 af1 = afl[(K2 + k) * 64 + lane];
            const f32x4 w0 = __builtin_amdgcn_mfma_f32_16x16x32_f16(af0, tnf, zc, 0, 0, 0);
            const f32x4 w1 = __builtin_amdgcn_mfma_f32_16x16x32_f16(af1, tnf, zc, 0, 0, 0);
#pragma unroll
            for (int reg = 0; reg < 4; ++reg) {
                acc0[reg] = fmaf(w0[reg], xc0[(size_t)reg * HWSZ + off] * m, acc0[reg]);
                acc1[reg] = fmaf(w1[reg], xc1[(size_t)reg * HWSZ + off] * m, acc1[reg]);
            }
        }
    }

    float* o0 = ob + (size_t)cb0 * HWSZ + y * WW + col;
    float* o1 = ob + (size_t)cb1 * HWSZ + y * WW + col;
#pragma unroll
    for (int reg = 0; reg < 4; ++reg) {
        o0[(size_t)reg * HWSZ] = acc0[reg];
        o1[(size_t)reg * HWSZ] = acc1[reg];
    }
}

extern "C" void kernel_launch(void* const* d_in, const int* in_sizes, int n_in,
                              void* d_out, int out_size, void* d_ws, size_t ws_size,
                              hipStream_t stream) {
    const float* x     = (const float*)d_in[0];
    const float* w1    = (const float*)d_in[1];
    const float* gamma = (const float*)d_in[2];
    const float* beta  = (const float*)d_in[3];
    const float* w2    = (const float*)d_in[4];
    const float* b2    = (const float*)d_in[5];
    float* out = (float*)d_out;

    float* ws = (float*)d_ws;

    k_prep<<<18, 256, 0, stream>>>(w2, b2, ws);

    dim3 gA(64, 8);
    k_conv1<<<gA, 256, 0, stream>>>(x, w1, ws + WS_T, ws + WS_PART);

    k_stats<<<128, 64, 0, stream>>>(ws + WS_PART, gamma, beta, ws + WS_STATS);

    k_norm<<<512, 256, 0, stream>>>(ws + WS_T, ws + WS_STATS, (f16x8*)(ws + WS_TN16));

    k_main<<<8192, 256, 0, stream>>>(x, ws, out);
}